// Round 1
// baseline (108.869 us; speedup 1.0000x reference)
//
#include <hip/hip_runtime.h>
#include <math.h>

#define NUM_H 256
#define NP    64        // poles per h
#define LL    8192      // sequence length
#define NHALF 4096      // LL/2
#define NF    4097      // LL/2 + 1
#define NT    512       // threads per block

__global__ __launch_bounds__(NT)
void ssk_nplr_kernel(const float* __restrict__ w_ri,
                     const float* __restrict__ p_ri,
                     const float* __restrict__ q_ri,
                     const float* __restrict__ B_ri,
                     const float* __restrict__ C_ri,
                     const float* __restrict__ log_dt,
                     float* __restrict__ out)
{
    __shared__ float2 s_wd[NP];        // discretized poles w*dt
    __shared__ float4 s_v[NP * 2];     // per n: {v00r,v00i,v01r,v01i},{v10r,v10i,v11r,v11i}
    __shared__ float2 s_G[NF];         // k_f spectrum (rfft bins)
    __shared__ float2 s_Z[NHALF];      // packed half-size complex FFT buffer

    const int h   = blockIdx.x;
    const int tid = threadIdx.x;
    const float dt = expf(log_dt[h]);

    // ---- Phase 0: per-h small data into LDS ----
    if (tid < NP) {
        const int n = tid;
        const float2 w = ((const float2*)w_ri)[h * NP + n];
        const float2 p = ((const float2*)p_ri)[h * NP + n];  // RANK=1
        const float2 q = ((const float2*)q_ri)[h * NP + n];
        const float2 B = ((const float2*)B_ri)[h * NP + n];
        const float2 C = ((const float2*)C_ri)[h * NP + n];  // CCH=1
        s_wd[n] = make_float2(w.x * dt, w.y * dt);
        // v[a][b] = Bc[b] * conj(Cc[a]);  Bc = {B, p}, Cc = {C, q}
        float4 vA, vB;
        vA.x = B.x * C.x + B.y * C.y;  vA.y = B.y * C.x - B.x * C.y;  // v00 = B*conj(C)
        vA.z = p.x * C.x + p.y * C.y;  vA.w = p.y * C.x - p.x * C.y;  // v01 = p*conj(C)
        vB.x = B.x * q.x + B.y * q.y;  vB.y = B.y * q.x - B.x * q.y;  // v10 = B*conj(q)
        vB.z = p.x * q.x + p.y * q.y;  vB.w = p.y * q.x - p.x * q.y;  // v11 = p*conj(q)
        s_v[2 * n]     = vA;
        s_v[2 * n + 1] = vB;
    }
    __syncthreads();

    // ---- Phase 1: Cauchy sum + Woodbury + bilinear factor -> s_G ----
    for (int l = tid; l < NF; l += NT) {
        // nodes = exp(-2*pi*i*l/L); z = 2(1-nodes)/(1+nodes); f = 2/(1+nodes)
        // Done in double, mirroring the reference's rounded-angle trig so the
        // l = L/2 bin stays finite (sin(-pi_rounded) != 0).
        double ang = -6.283185307179586476925286766559 * (double)l / (double)LL;
        double nr = cos(ang), ni = sin(ang);
        double dr = 1.0 + nr, di = ni;
        double den = dr * dr + di * di;
        if (den < 1e-280) den = 1e-280;   // graceful fallback, bin ~0
        double onr = 1.0 - nr, oni = -ni;
        const float zr = (float)(2.0 * (onr * dr + oni * di) / den);
        const float y  = (float)(2.0 * (oni * dr - onr * di) / den);  // Im(z)
        const float fr = (float)( 2.0 * dr / den);
        const float fi = (float)(-2.0 * di / den);

        float a00r = 0.f, a00i = 0.f, a01r = 0.f, a01i = 0.f;
        float a10r = 0.f, a10i = 0.f, a11r = 0.f, a11i = 0.f;
        #pragma unroll 8
        for (int n = 0; n < NP; ++n) {
            const float2 wd = s_wd[n];
            const float xr = zr - wd.x;          // Re(z - wd) = Re(z - conj(wd))
            const float t1 = y - wd.y;           // Im(z - wd)
            const float t2 = y + wd.y;           // Im(z - conj(wd))
            const float xr2 = xr * xr;
            const float i1 = __builtin_amdgcn_rcpf(xr2 + t1 * t1);
            const float i2 = __builtin_amdgcn_rcpf(xr2 + t2 * t2);
            const float c1r = xr * i1, c1i = -t1 * i1;   // 1/(z - wd)
            const float c2r = xr * i2, c2i = -t2 * i2;   // 1/(z - conj(wd))
            // v*c1 + conj(v)*c2 = Re(v)*(c1+c2) + i*Im(v)*(c1-c2)
            const float Sr = c1r + c2r, Si = c1i + c2i;
            const float Dr = c2i - c1i, Di = c1r - c2r;
            const float4 vA = s_v[2 * n];
            const float4 vB = s_v[2 * n + 1];
            a00r += vA.x * Sr + vA.y * Dr;  a00i += vA.x * Si + vA.y * Di;
            a01r += vA.z * Sr + vA.w * Dr;  a01i += vA.z * Si + vA.w * Di;
            a10r += vB.x * Sr + vB.y * Dr;  a10i += vB.x * Si + vB.y * Di;
            a11r += vB.z * Sr + vB.w * Dr;  a11i += vB.z * Si + vB.w * Di;
        }
        a00r *= dt; a00i *= dt; a01r *= dt; a01i *= dt;
        a10r *= dt; a10i *= dt; a11r *= dt; a11i *= dt;

        // Woodbury: kf = a00 - a01*a10/(1 + a11)
        const float numr = a01r * a10r - a01i * a10i;
        const float numi = a01r * a10i + a01i * a10r;
        const float dwr = 1.f + a11r, dwi = a11i;
        const float idw = __builtin_amdgcn_rcpf(dwr * dwr + dwi * dwi);
        const float qr = (numr * dwr + numi * dwi) * idw;
        const float qi = (numi * dwr - numr * dwi) * idw;
        float kfr = a00r - qr, kfi = a00i - qi;

        // kf *= 2/(1+nodes)
        const float orr = kfr * fr - kfi * fi;
        const float ori = kfr * fi + kfi * fr;
        s_G[l] = make_float2(orr, ori);
    }
    __syncthreads();

    // ---- Phase 2: pack irfft(L) as complex iFFT(L/2), bit-reversed writes ----
    // Z[k] = (1/L)[ (G[k]+conj(G[N-k])) + i*e^{+2pi i k/L}*(G[k]-conj(G[N-k])) ]
    for (int k = tid; k < NHALF; k += NT) {
        const float2 Gk = s_G[k];
        const float2 Gn = s_G[NHALF - k];
        const float Ar = Gk.x + Gn.x, Ai = Gk.y - Gn.y;
        const float Br = Gk.x - Gn.x, Bi = Gk.y + Gn.y;
        const float ang = 7.66990393942820615e-4f * (float)k;  // 2*pi/8192 * k
        float sw, cw;
        sincosf(ang, &sw, &cw);
        const float Zr = (Ar - cw * Bi - sw * Br) * (1.0f / (float)LL);
        const float Zi = (Ai + cw * Br - sw * Bi) * (1.0f / (float)LL);
        const int rev = (int)(__brev((unsigned)k) >> 20);   // 12-bit reversal
        s_Z[rev] = make_float2(Zr, Zi);
    }
    __syncthreads();

    // ---- Phase 3: in-place radix-2 DIT inverse FFT (sign +1), N = 4096 ----
    for (int len = 2; len <= NHALF; len <<= 1) {
        const int half = len >> 1;
        for (int i = tid; i < (NHALF >> 1); i += NT) {
            const int j = i & (half - 1);
            const int g = (i - j) << 1;
            const float ang = 6.28318530717958648f * (float)j / (float)len;
            float sw, cw;
            sincosf(ang, &sw, &cw);
            const float2 u = s_Z[g + j];
            const float2 t = s_Z[g + j + half];
            const float tr = cw * t.x - sw * t.y;
            const float ti = cw * t.y + sw * t.x;
            s_Z[g + j]        = make_float2(u.x + tr, u.y + ti);
            s_Z[g + j + half] = make_float2(u.x - tr, u.y - ti);
        }
        __syncthreads();
    }

    // ---- Phase 4: x[2j] = Re z[j], x[2j+1] = Im z[j]; coalesced float2 store ----
    float2* orow = (float2*)(out + (size_t)h * LL);
    for (int j = tid; j < NHALF; j += NT) {
        orow[j] = s_Z[j];
    }
}

extern "C" void kernel_launch(void* const* d_in, const int* in_sizes, int n_in,
                              void* d_out, int out_size, void* d_ws, size_t ws_size,
                              hipStream_t stream) {
    const float* w   = (const float*)d_in[0];
    const float* p   = (const float*)d_in[1];
    const float* q   = (const float*)d_in[2];
    const float* B   = (const float*)d_in[3];
    const float* C   = (const float*)d_in[4];
    const float* ldt = (const float*)d_in[5];
    ssk_nplr_kernel<<<NUM_H, NT, 0, stream>>>(w, p, q, B, C, ldt, (float*)d_out);
}